// Round 6
// baseline (569.722 us; speedup 1.0000x reference)
//
#include <hip/hip_runtime.h>
#include <stdint.h>

// Problem constants
#define TB 4
#define TT 8192
#define TD 1024
#define TS 32
#define TL 256
#define BT 32768   // TB*TT

typedef unsigned short u16;
typedef __bf16 bf16x8 __attribute__((ext_vector_type(8)));
typedef float f32x4 __attribute__((ext_vector_type(4)));

typedef uint32_t u32_g __attribute__((address_space(1)));
typedef uint32_t u32_l __attribute__((address_space(3)));

#define VMWAIT(N) asm volatile("s_waitcnt vmcnt(" #N ")" ::: "memory")
#define LGKM(N)   asm volatile("s_waitcnt lgkmcnt(" #N ")" ::: "memory")

__device__ __forceinline__ u16 f2b(float f){
  union { float f; uint32_t u; } a; a.f = f;
  uint32_t r = a.u + 0x7FFFu + ((a.u >> 16) & 1u);
  return (u16)(r >> 16);
}
__device__ __forceinline__ float b2f(u16 u){
  union { uint32_t u; float f; } a; a.u = ((uint32_t)u) << 16;
  return a.f;
}
__device__ __forceinline__ void gll16(const void* g, void* l){
  __builtin_amdgcn_global_load_lds((const u32_g*)g, (u32_l*)l, 16, 0, 0);
}

// ---- merged prep: blocks 0..2047 convert gw/ow -> bf16; 2048..2175 compute q = ms @ Wq^T ----
__global__ void k_prep0(const float* __restrict__ gw, const float* __restrict__ ow,
                        u16* __restrict__ gwb, u16* __restrict__ owb,
                        const float* __restrict__ ms, const float* __restrict__ Wq,
                        float* __restrict__ q){
  __shared__ float sm[TD];
  int bid = blockIdx.x, tid = threadIdx.x;
  if (bid < 2048){
    int i = bid*256 + tid;   // 0 .. 524287
    const float* src; u16* dst; int j;
    if (i < 262144){ src = gw; dst = gwb; j = i; }
    else           { src = ow; dst = owb; j = i - 262144; }
    float4 v = ((const float4*)src)[j];
    ushort4 u; u.x=f2b(v.x); u.y=f2b(v.y); u.z=f2b(v.z); u.w=f2b(v.w);
    ((ushort4*)dst)[j] = u;
  } else {
    int idx = bid - 2048;            // 0..127
    int s = idx >> 2, chunk = idx & 3;
    int d = chunk*256 + tid;
    for (int i = tid; i < TD; i += 256) sm[i] = ms[s*TD + i];
    __syncthreads();
    const float* w = Wq + (size_t)d*TD;
    float a0=0.f, a1=0.f;
    for (int e=0; e<TD; e+=8){
      float4 w0 = *(const float4*)(w+e);
      float4 w1 = *(const float4*)(w+e+4);
      a0 += w0.x*sm[e]   + w0.y*sm[e+1] + w0.z*sm[e+2] + w0.w*sm[e+3];
      a1 += w1.x*sm[e+4] + w1.y*sm[e+5] + w1.z*sm[e+6] + w1.w*sm[e+7];
    }
    q[(size_t)s*TD + d] = a0 + a1;
  }
}

// ---- qk[s,e] = scale * sum_d q[s,d] * Wk[d,e]  -- grid (32 s, 4 e-chunks), d split 4-way ----
__global__ void k_prep_qk(const float* __restrict__ q, const float* __restrict__ Wk,
                          float* __restrict__ qk){
  __shared__ float sq[TD];
  __shared__ f32x4 part[4][64];
  int s = blockIdx.x;
  int tid = threadIdx.x;
  int ds = tid >> 6, e4 = tid & 63;
  int e = blockIdx.y*256 + e4*4;
  for (int i = tid; i < TD; i += 256) sq[i] = q[s*TD + i];
  __syncthreads();
  f32x4 acc = {0,0,0,0};
  int d0 = ds*256;
  #pragma unroll 4
  for (int d = d0; d < d0+256; ++d){
    float4 w = *(const float4*)(Wk + (size_t)d*TD + e);
    float sv = sq[d];
    acc[0] += sv*w.x; acc[1] += sv*w.y; acc[2] += sv*w.z; acc[3] += sv*w.w;
  }
  part[ds][e4] = acc;
  __syncthreads();
  if (ds == 0){
    f32x4 t = part[0][e4];
    f32x4 t1 = part[1][e4], t2 = part[2][e4], t3 = part[3][e4];
    const float scale = 1.0f/32.0f;
    float4 o;
    o.x = (t[0]+t1[0]+t2[0]+t3[0])*scale;
    o.y = (t[1]+t1[1]+t2[1]+t3[1])*scale;
    o.z = (t[2]+t1[2]+t2[2]+t3[2])*scale;
    o.w = (t[3]+t1[3]+t2[3]+t3[3])*scale;
    *(float4*)(qk + (size_t)s*TD + e) = o;
  }
}

// ---- single pass over x: convert to bf16 AND compute write logits wqk[bt] ----
__global__ void k_conv_dot(const float* __restrict__ x, const float* __restrict__ qk,
                           u16* __restrict__ xb, float* __restrict__ wqk){
  int lane = threadIdx.x & 63, wv = threadIdx.x >> 6;
  long bt0 = (long)blockIdx.x * 16;
  int sseg = (int)((bt0 & (TT-1)) >> 8);   // uniform across block (16 | 256)
  float qv[16];
  #pragma unroll
  for (int i=0;i<4;i++){
    float4 t = *(const float4*)(qk + (size_t)sseg*TD + i*256 + lane*4);
    qv[i*4+0]=t.x; qv[i*4+1]=t.y; qv[i*4+2]=t.z; qv[i*4+3]=t.w;
  }
  for (int tok = wv; tok < 16; tok += 4){
    long bt = bt0 + tok;
    const float* xr = x + bt*TD;
    float dot = 0.f;
    #pragma unroll
    for (int i=0;i<4;i++){
      float4 t = *(const float4*)(xr + i*256 + lane*4);
      ushort4 u; u.x=f2b(t.x); u.y=f2b(t.y); u.z=f2b(t.z); u.w=f2b(t.w);
      *(ushort4*)(xb + bt*TD + i*256 + lane*4) = u;
      dot += t.x*qv[i*4] + t.y*qv[i*4+1] + t.z*qv[i*4+2] + t.w*qv[i*4+3];
    }
    #pragma unroll
    for (int o=32;o;o>>=1) dot += __shfl_xor(dot, o);
    if (lane == 0) wqk[bt] = dot;
  }
}

// ---- per (b,s,dchunk): softmax (recomputed per block), xbar d-slice ----
// 4 row-groups (1 wave each) x ushort4 loads; LDS reduce of partials.
__global__ void k_wattn(const float* __restrict__ wqk, const u16* __restrict__ xb,
                        float* __restrict__ xbar){
  __shared__ float sw[TL];
  __shared__ float red[8];
  __shared__ f32x4 part[4][64];
  int tid = threadIdx.x, lane = tid & 63, wv = tid >> 6;
  int b = blockIdx.x >> 5, s = blockIdx.x & 31;
  long base = (long)b*TT + (long)s*TL;
  float v = wqk[base + tid];
  float m = v;
  #pragma unroll
  for (int o=32;o;o>>=1) m = fmaxf(m, __shfl_xor(m, o));
  if (lane == 0) red[wv] = m;
  __syncthreads();
  m = fmaxf(fmaxf(red[0], red[1]), fmaxf(red[2], red[3]));
  float e = __expf(v - m);
  float sm = e;
  #pragma unroll
  for (int o=32;o;o>>=1) sm += __shfl_xor(sm, o);
  if (lane == 0) red[4+wv] = sm;
  __syncthreads();
  sm = red[4]+red[5]+red[6]+red[7];
  sw[tid] = e / sm;
  __syncthreads();
  // wave wv handles rows [wv*64, wv*64+64); lane owns 4 consecutive d
  int d = blockIdx.y*256 + lane*4;
  const u16* xp = xb + (base + wv*64)*TD + d;
  f32x4 acc = {0,0,0,0};
  #pragma unroll 8
  for (int i=0; i<64; ++i){
    float w = sw[wv*64 + i];
    ushort4 u = *(const ushort4*)(xp + (size_t)i*TD);
    acc[0] += w*b2f(u.x); acc[1] += w*b2f(u.y); acc[2] += w*b2f(u.z); acc[3] += w*b2f(u.w);
  }
  part[wv][lane] = acc;
  __syncthreads();
  if (wv == 0){
    f32x4 t0 = part[0][lane], t1 = part[1][lane], t2 = part[2][lane], t3 = part[3][lane];
    float4 o;
    o.x = t0[0]+t1[0]+t2[0]+t3[0];
    o.y = t0[1]+t1[1]+t2[1]+t3[1];
    o.z = t0[2]+t1[2]+t2[2]+t3[2];
    o.w = t0[3]+t1[3]+t2[3]+t3[3];
    *(float4*)(xbar + ((size_t)b*TS + s)*TD + d) = o;
  }
}

// ---- small matmul: C[128,1024] = A[128,1024] @ (modeT ? W^T : W), multi-format output ----
__global__ void k_mm(const float* __restrict__ A, const float* __restrict__ W,
                     int modeT, float scale,
                     float* __restrict__ Cf, float* __restrict__ Cf2,
                     u16* __restrict__ Cb, u16* __restrict__ CbT){
  __shared__ float sA[2][TD];
  int r0 = blockIdx.x*2;
  int n = blockIdx.y*256 + threadIdx.x;
  for (int i=threadIdx.x; i<2*TD; i+=256) sA[i>>10][i&1023] = A[(size_t)r0*TD + i];
  __syncthreads();
  float acc0=0.f, acc1=0.f;
  if (modeT){
    const float* w = W + (size_t)n*TD;
    for (int k=0;k<TD;k+=4){
      float4 wv = *(const float4*)(w+k);
      float4 a0 = *(const float4*)(&sA[0][k]);
      float4 a1 = *(const float4*)(&sA[1][k]);
      acc0 += wv.x*a0.x + wv.y*a0.y + wv.z*a0.z + wv.w*a0.w;
      acc1 += wv.x*a1.x + wv.y*a1.y + wv.z*a1.z + wv.w*a1.w;
    }
  } else {
    for (int k=0;k<TD;k+=4){
      float w0 = W[(size_t)k*TD + n],     w1 = W[(size_t)(k+1)*TD + n];
      float w2 = W[(size_t)(k+2)*TD + n], w3 = W[(size_t)(k+3)*TD + n];
      float4 a0 = *(const float4*)(&sA[0][k]);
      float4 a1 = *(const float4*)(&sA[1][k]);
      acc0 += w0*a0.x + w1*a0.y + w2*a0.z + w3*a0.w;
      acc1 += w0*a1.x + w1*a1.y + w2*a1.z + w3*a1.w;
    }
  }
  #pragma unroll
  for (int r=0;r<2;r++){
    float v = (r==0?acc0:acc1)*scale;
    int rr = r0 + r;
    size_t idx = (size_t)rr*TD + n;
    if (Cf)  Cf[idx]  = v;
    if (Cf2) Cf2[idx] = v;
    if (Cb)  Cb[idx]  = f2b(v);
    if (CbT){ int bb = rr >> 5, ss = rr & 31; CbT[((size_t)bb*TD + n)*TS + ss] = f2b(v); }
  }
}

// ---- merged rk/rv matmuls (same A=memory, modeT): z=0 -> rkbf f32, z=1 -> rvT bf16 transposed ----
__global__ void k_mm23(const float* __restrict__ A, const float* __restrict__ W0,
                       const float* __restrict__ W1,
                       float* __restrict__ rkbf, u16* __restrict__ rvT){
  __shared__ float sA[2][TD];
  const float* W = blockIdx.z ? W1 : W0;
  int r0 = blockIdx.x*2;
  int n = blockIdx.y*256 + threadIdx.x;
  for (int i=threadIdx.x; i<2*TD; i+=256) sA[i>>10][i&1023] = A[(size_t)r0*TD + i];
  __syncthreads();
  float acc0=0.f, acc1=0.f;
  const float* w = W + (size_t)n*TD;
  for (int k=0;k<TD;k+=4){
    float4 wv = *(const float4*)(w+k);
    float4 a0 = *(const float4*)(&sA[0][k]);
    float4 a1 = *(const float4*)(&sA[1][k]);
    acc0 += wv.x*a0.x + wv.y*a0.y + wv.z*a0.z + wv.w*a0.w;
    acc1 += wv.x*a1.x + wv.y*a1.y + wv.z*a1.z + wv.w*a1.w;
  }
  #pragma unroll
  for (int r=0;r<2;r++){
    float v = (r==0?acc0:acc1);
    int rr = r0 + r;
    if (blockIdx.z == 0){
      rkbf[(size_t)rr*TD + n] = v;
    } else {
      int bb = rr >> 5, ss = rr & 31;
      rvT[((size_t)bb*TD + n)*TS + ss] = f2b(v);
    }
  }
}

// ---- read-attention weights: QK^T (MFMA) + masked softmax -> normalized P [BT][32] bf16 ----
__global__ __launch_bounds__(256) void k_pattn(const u16* __restrict__ xb, const u16* __restrict__ rkb,
                                               u16* __restrict__ P){
  int tid = threadIdx.x, lane = tid & 63, wv = tid >> 6;
  long bt0 = (long)blockIdx.x * 64;
  int b = (int)(bt0 >> 13);
  int smin = (int)((bt0 & (TT-1)) >> 8);
  int r15 = lane & 15, kg = lane >> 4;

  long tw = bt0 + wv*16;
  const u16* ap  = xb  + (size_t)(tw + r15)*TD + kg*8;
  const u16* bp0 = rkb + ((size_t)(b*TS + r15))*TD + kg*8;
  const u16* bp1 = rkb + ((size_t)(b*TS + 16 + r15))*TD + kg*8;
  f32x4 p0 = {0,0,0,0}, p1 = {0,0,0,0};
  #pragma unroll 4
  for (int ks=0; ks<32; ++ks){
    bf16x8 a  = *(const bf16x8*)(ap  + ks*32);
    bf16x8 b0 = *(const bf16x8*)(bp0 + ks*32);
    bf16x8 b1 = *(const bf16x8*)(bp1 + ks*32);
    p0 = __builtin_amdgcn_mfma_f32_16x16x32_bf16(a, b0, p0, 0,0,0);
    p1 = __builtin_amdgcn_mfma_f32_16x16x32_bf16(a, b1, p1, 0,0,0);
  }
  bool msk0 = (r15 < smin), msk1 = (16 + r15 < smin);
  #pragma unroll
  for (int q=0;q<4;q++){
    float l0 = msk0 ? -1e30f : p0[q];
    float l1 = msk1 ? -1e30f : p1[q];
    float mx = fmaxf(l0, l1);
    #pragma unroll
    for (int o=1;o<16;o<<=1) mx = fmaxf(mx, __shfl_xor(mx, o));
    float e0 = msk0 ? 0.f : __expf(l0 - mx);
    float e1 = msk1 ? 0.f : __expf(l1 - mx);
    float smv = e0 + e1;
    #pragma unroll
    for (int o=1;o<16;o<<=1) smv += __shfl_xor(smv, o);
    float rs = 1.f/smv;
    long trow = tw + 4*kg + q;
    P[trow*TS + r15]      = f2b(e0*rs);
    P[trow*TS + 16 + r15] = f2b(e1*rs);
  }
}

// ---- big MFMA GEMM: C[32768,1024] = A @ W^T  (A bf16 [M][K], W bf16 [N][K]) ----
// 256x256 tile, 512 threads (8 waves 2x4), BK=32, 4-slot LDS ring (128KB),
// counted vmcnt; all 12 ds_reads issued up front with lgkmcnt(4) before
// phase-0 MFMA (af2 drains during phase-0 compute), lgkmcnt(0) before phase-1.
// XOR-swizzled LDS reads, linear gll16 dest with pre-inverse-swizzled source.
template<bool SIG>
__global__ __launch_bounds__(512, 2) void k_gemm(const u16* __restrict__ A, const u16* __restrict__ Bw,
                                                 const float* __restrict__ bias, void* __restrict__ Cp,
                                                 const u16* __restrict__ P, const u16* __restrict__ rvT){
  __shared__ __align__(16) char sL[131072];
  int tid = threadIdx.x, lane = tid & 63, wv = tid >> 6;
  int bid = blockIdx.x;
  int wg = ((bid & 7) << 6) | (bid >> 3);   // XCD swizzle, 512 % 8 == 0 -> bijective
  int nt = wg & 3, mt = wg >> 2;
  int m0 = mt*256, n0 = nt*256;
  int wr = wv >> 2, wc = wv & 3;            // wave -> (m-half, n-quarter)
  int r15 = lane & 15, kg = lane >> 4;

  // LDS read byte-offsets (swizzled), constant over K-loop
  int ard[8], brd[4];
  #pragma unroll
  for (int i=0;i<8;i++){ int row = wr*128 + i*16 + r15; ard[i] = (row*64 + kg*16) ^ ((row&7)<<4); }
  #pragma unroll
  for (int j=0;j<4;j++){ int row = wc*64  + j*16 + r15; brd[j] = (row*64 + kg*16) ^ ((row&7)<<4); }

  // stage: linear LDS dest (gll16 = uniform base + lane*16); pre-inverse-swizzled global source.
  const u16* asrc[2]; const u16* bsrc[2]; int ldst[2];
  #pragma unroll
  for (int r=0;r<2;r++){
    int S  = (r*8 + wv)*64 + lane;
    int r1 = (S>>3)&1, r2 = (S>>4)&1;
    int r0 = ((S>>2)&1) ^ r2;
    int row = ((S>>3)<<1) | r0;
    int kh  = (S&3) ^ ((r1<<1) | r0);
    asrc[r] = A  + (size_t)(m0 + row)*TD + kh*8;
    bsrc[r] = Bw + (size_t)(n0 + row)*TD + kh*8;
    ldst[r] = (r*8 + wv)*1024;
  }

  f32x4 acc[8][4];
  #pragma unroll
  for (int i=0;i<8;i++){
    #pragma unroll
    for (int j=0;j<4;j++){ f32x4 z = {0,0,0,0}; acc[i][j] = z; }
  }

  auto stageA = [&](int t){
    char* slot = sL + (size_t)(t&3)*32768;
    int k0 = t*32;
    gll16(asrc[0] + k0, slot + ldst[0]);
    gll16(asrc[1] + k0, slot + ldst[1]);
  };
  auto stageB = [&](int t){
    char* slot = sL + (size_t)(t&3)*32768;
    int k0 = t*32;
    gll16(bsrc[0] + k0, slot + 16384 + ldst[0]);
    gll16(bsrc[1] + k0, slot + 16384 + ldst[1]);
  };

  auto tile = [&](int t, bool prefetch){
    const char* sa = sL + (size_t)(t&3)*32768;
    const char* sb = sa + 16384;
    bf16x8 bfg[4], af[4], af2[4];
    // all 12 reads up front (in-order completion: bfg, af, then af2)
    #pragma unroll
    for (int j=0;j<4;j++) bfg[j] = *(const bf16x8*)(sb + brd[j]);
    #pragma unroll
    for (int i=0;i<4;i++) af[i] = *(const bf16x8*)(sa + ard[i]);
    #pragma unroll
    for (int i=0;i<4;i++) af2[i] = *(const bf16x8*)(sa + ard[4+i]);
    if (prefetch) stageA(t+3);
    __builtin_amdgcn_sched_barrier(0);
    __builtin_amdgcn_s_barrier();
    LGKM(4);                              // bfg+af complete; af2 still draining
    __builtin_amdgcn_sched_barrier(0);
    __builtin_amdgcn_s_setprio(1);
    #pragma unroll
    for (int i=0;i<4;i++){
      #pragma unroll
      for (int j=0;j<4;j++)
        acc[i][j] = __builtin_amdgcn_mfma_f32_16x16x32_bf16(af[i], bfg[j], acc[i][j], 0,0,0);
    }
    __builtin_amdgcn_s_setprio(0);
    if (prefetch) stageB(t+3);
    __builtin_amdgcn_s_barrier();
    LGKM(0);
    __builtin_amdgcn_sched_barrier(0);
    __builtin_amdgcn_s_setprio(1);
    #pragma unroll
    for (int i=0;i<4;i++){
      #pragma unroll
      for (int j=0;j<4;j++)
        acc[4+i][j] = __builtin_amdgcn_mfma_f32_16x16x32_bf16(af2[i], bfg[j], acc[4+i][j], 0,0,0);
    }
    __builtin_amdgcn_s_setprio(0);
  };

  stageA(0); stageB(0); stageA(1); stageB(1); stageA(2); stageB(2);

  for (int t=0; t<30; ++t){
    VMWAIT(8);
    __builtin_amdgcn_s_barrier();
    tile(t, t < 29);
  }
  VMWAIT(4); __builtin_amdgcn_s_barrier(); tile(30, false);
  VMWAIT(0); __builtin_amdgcn_s_barrier(); tile(31, false);

  // epilogue: C row = kg*4+q, col = r15
  if (SIG){
    int b = m0 >> 13;
    bf16x8 vfrag[4];
    #pragma unroll
    for (int j=0;j<4;j++){
      int n = n0 + wc*64 + j*16 + r15;
      vfrag[j] = *(const bf16x8*)(rvT + ((size_t)b*TD + n)*TS + kg*8);
    }
    #pragma unroll
    for (int i=0;i<8;i++){
      int tokbase = m0 + wr*128 + i*16;
      bf16x8 pfrag = *(const bf16x8*)(P + (size_t)(tokbase + r15)*TS + kg*8);
      f32x4 rd[4];
      #pragma unroll
      for (int j=0;j<4;j++){
        f32x4 z = {0,0,0,0};
        rd[j] = __builtin_amdgcn_mfma_f32_16x16x32_bf16(pfrag, vfrag[j], z, 0,0,0);
      }
      int mrow = tokbase + kg*4;
      #pragma unroll
      for (int j=0;j<4;j++){
        int n = n0 + wc*64 + j*16 + r15;
        float bj = bias[n];
        #pragma unroll
        for (int q=0;q<4;q++){
          float g = 1.f/(1.f + __expf(-(acc[i][j][q] + bj)));
          size_t idx = (size_t)(mrow + q)*TD + n;
          float xv = b2f(A[idx]);   // A == xb
          ((u16*)Cp)[idx] = f2b(xv + g*rd[j][q]);
        }
      }
    }
  } else {
    #pragma unroll
    for (int i=0;i<8;i++){
      int mrow = m0 + wr*128 + i*16 + kg*4;
      #pragma unroll
      for (int j=0;j<4;j++){
        int n = n0 + wc*64 + j*16 + r15;
        #pragma unroll
        for (int q=0;q<4;q++){
          size_t idx = (size_t)(mrow + q)*TD + n;
          ((float*)Cp)[idx] = acc[i][j][q];
        }
      }
    }
  }
}

extern "C" void kernel_launch(void* const* d_in, const int* in_sizes, int n_in,
                              void* d_out, int out_size, void* d_ws, size_t ws_size,
                              hipStream_t stream){
  const float* x   = (const float*)d_in[0];
  const float* gw  = (const float*)d_in[1];
  const float* gb  = (const float*)d_in[2];
  const float* rqw = (const float*)d_in[3];
  const float* rkw = (const float*)d_in[4];
  const float* rvw = (const float*)d_in[5];
  const float* ow  = (const float*)d_in[6];
  const float* ms  = (const float*)d_in[7];
  const float* wqw = (const float*)d_in[8];
  const float* wkw = (const float*)d_in[9];
  const float* wvw = (const float*)d_in[10];
  float* out = (float*)d_out;
  float* mem_out = out + (size_t)BT*TD;

  // xb (bf16 copy of x, 64MB) lives in the front 64MB of d_out; P (2MB) in
  // the second 64MB. Both dead before the final GEMM overwrites d_out.
  u16* xb = (u16*)d_out;
  u16* Pb = (u16*)((char*)d_out + 67108864);

  char* w = (char*)d_ws;
  u16*   gy    = (u16*)(w);                    // 64MB  (y = x + g*read)
  float* wqkb  = (float*)(w + 67108864);       // 128KB
  float* qb    = (float*)(w + 67239936);       // 128KB
  float* qkb   = (float*)(w + 67371008);       // 128KB
  float* xbarb = (float*)(w + 67502080);       // 512KB
  float* memb  = (float*)(w + 68026368);       // 512KB
  float* rkbf  = (float*)(w + 68550656);       // 512KB
  u16*   rkb   = (u16*)(w + 69074944);         // 256KB
  u16*   rvT   = (u16*)(w + 69337088);         // 256KB
  u16*   gwb   = (u16*)(w + 69599232);         // 2MB
  u16*   owb   = (u16*)(w + 71696384);         // 2MB

  k_prep0<<<2176,256,0,stream>>>(gw, ow, gwb, owb, ms, wqw, qb);
  k_prep_qk<<<dim3(32,4),256,0,stream>>>(qb, wkw, qkb);
  k_conv_dot<<<2048,256,0,stream>>>(x, qkb, xb, wqkb);
  k_wattn<<<dim3(128,4),256,0,stream>>>(wqkb, xb, xbarb);
  // memory = xbar @ Wv^T   (also written to output slot 1)
  k_mm<<<dim3(64,4),256,0,stream>>>(xbarb, wvw, 1, 1.f, memb, mem_out, nullptr, nullptr);
  // rk = memory @ Wrk^T ; rv = memory @ Wrv^T -> transposed bf16 [b][d][s]
  k_mm23<<<dim3(64,4,2),256,0,stream>>>(memb, rkw, rvw, rkbf, rvT);
  // rk~ = scale * rk @ Wrq -> bf16 [b*s][d]
  k_mm<<<dim3(64,4),256,0,stream>>>(rkbf, rqw, 0, 1.f/32.f, nullptr, nullptr, rkb, nullptr);
  // P = softmax(mask(xb @ rk~^T)) normalized, bf16 [BT][32]
  k_pattn<<<512,256,0,stream>>>(xb, rkb, Pb);
  // y = x + sigmoid(x@gate_w^T + gb) * (P @ rvT)   [fused]
  k_gemm<true><<<512,512,0,stream>>>(xb, gwb, gb, gy, Pb, rvT);
  // out = y @ output_w^T
  k_gemm<false><<<512,512,0,stream>>>(gy, owb, nullptr, d_out, nullptr, nullptr);
}

// Round 7
// 458.332 us; speedup vs baseline: 1.2430x; 1.2430x over previous
//
#include <hip/hip_runtime.h>
#include <stdint.h>

// Problem constants
#define TB 4
#define TT 8192
#define TD 1024
#define TS 32
#define TL 256
#define BT 32768   // TB*TT

typedef unsigned short u16;
typedef __bf16 bf16x8 __attribute__((ext_vector_type(8)));
typedef float f32x4 __attribute__((ext_vector_type(4)));

typedef uint32_t u32_g __attribute__((address_space(1)));
typedef uint32_t u32_l __attribute__((address_space(3)));

#define VMWAIT(N) asm volatile("s_waitcnt vmcnt(" #N ")" ::: "memory")
#define LGKM0()   asm volatile("s_waitcnt lgkmcnt(0)" ::: "memory")

__device__ __forceinline__ u16 f2b(float f){
  union { float f; uint32_t u; } a; a.f = f;
  uint32_t r = a.u + 0x7FFFu + ((a.u >> 16) & 1u);
  return (u16)(r >> 16);
}
__device__ __forceinline__ float b2f(u16 u){
  union { uint32_t u; float f; } a; a.u = ((uint32_t)u) << 16;
  return a.f;
}
__device__ __forceinline__ void gll16(const void* g, void* l){
  __builtin_amdgcn_global_load_lds((const u32_g*)g, (u32_l*)l, 16, 0, 0);
}

// ---- convert 6 weight matrices + ms -> bf16 (linear, coalesced) ----
// grid 6176: bid/1024 -> matrix (0..5), bid>=6144 -> ms (32 blocks)
__global__ void k_convw(const float* __restrict__ s0, const float* __restrict__ s1,
                        const float* __restrict__ s2, const float* __restrict__ s3,
                        const float* __restrict__ s4, const float* __restrict__ s5,
                        const float* __restrict__ s6,
                        u16* __restrict__ d0, u16* __restrict__ d1,
                        u16* __restrict__ d2, u16* __restrict__ d3,
                        u16* __restrict__ d4, u16* __restrict__ d5,
                        u16* __restrict__ d6){
  int bid = blockIdx.x, tid = threadIdx.x;
  const float* src; u16* dst; int j;
  if (bid >= 6144){ src = s6; dst = d6; j = (bid - 6144)*256 + tid; }
  else {
    int mi = bid >> 10;
    j = (bid & 1023)*256 + tid;
    if      (mi == 0){ src = s0; dst = d0; }
    else if (mi == 1){ src = s1; dst = d1; }
    else if (mi == 2){ src = s2; dst = d2; }
    else if (mi == 3){ src = s3; dst = d3; }
    else if (mi == 4){ src = s4; dst = d4; }
    else             { src = s5; dst = d5; }
  }
  float4 v = ((const float4*)src)[j];
  ushort4 u; u.x=f2b(v.x); u.y=f2b(v.y); u.z=f2b(v.z); u.w=f2b(v.w);
  ((ushort4*)dst)[j] = u;
}

// ---- q[32,1024] = ms @ Wq^T via register MFMA (8 blocks x 512 thr) ----
__global__ __launch_bounds__(512) void k_q32(const u16* __restrict__ msb, const u16* __restrict__ Wqb,
                                             float* __restrict__ q){
  int tid = threadIdx.x, lane = tid & 63, wv = tid >> 6;
  int r15 = lane & 15, kg = lane >> 4;
  int n0 = blockIdx.x*128 + wv*16;
  const u16* ap = msb + (size_t)r15*TD + kg*8;
  const u16* bp = Wqb + (size_t)(n0 + r15)*TD + kg*8;
  f32x4 a0 = {0,0,0,0}, a1 = {0,0,0,0};
  #pragma unroll 4
  for (int k0=0; k0<TD; k0+=32){
    bf16x8 b  = *(const bf16x8*)(bp + k0);
    bf16x8 x0 = *(const bf16x8*)(ap + k0);
    bf16x8 x1 = *(const bf16x8*)(ap + 16*TD + k0);
    a0 = __builtin_amdgcn_mfma_f32_16x16x32_bf16(x0, b, a0, 0,0,0);
    a1 = __builtin_amdgcn_mfma_f32_16x16x32_bf16(x1, b, a1, 0,0,0);
  }
  #pragma unroll
  for (int qq=0; qq<4; ++qq){
    q[(size_t)(kg*4 + qq)*TD + n0 + r15]      = a0[qq];
    q[(size_t)(16 + kg*4 + qq)*TD + n0 + r15] = a1[qq];
  }
}

// ---- C[128,1024] = A(bf16) @ W(bf16)^T via register MFMA; multi-format epilogue ----
// grid (8, 1, Z): z=0 -> oF0 (f32) and/or oB0 (bf16); z=1 -> oBT1 (bf16 [b][d][s])
__global__ __launch_bounds__(512) void k_smm128(const u16* __restrict__ A,
                                                const u16* __restrict__ W0, const u16* __restrict__ W1,
                                                float* __restrict__ oF0, u16* __restrict__ oB0,
                                                u16* __restrict__ oBT1){
  int tid = threadIdx.x, lane = tid & 63, wv = tid >> 6;
  int r15 = lane & 15, kg = lane >> 4;
  int wr = wv >> 2, wc = wv & 3;
  int n0 = blockIdx.x*128 + wc*32;
  const u16* W = blockIdx.z ? W1 : W0;
  const u16* ap = A + (size_t)(wr*64 + r15)*TD + kg*8;
  const u16* bp = W + (size_t)(n0 + r15)*TD + kg*8;
  f32x4 acc[4][2];
  #pragma unroll
  for (int i=0;i<4;i++){ f32x4 z={0,0,0,0}; acc[i][0]=z; acc[i][1]=z; }
  #pragma unroll 2
  for (int k0=0; k0<TD; k0+=32){
    bf16x8 b0 = *(const bf16x8*)(bp + k0);
    bf16x8 b1 = *(const bf16x8*)(bp + 16*TD + k0);
    bf16x8 a0 = *(const bf16x8*)(ap + k0);
    bf16x8 a1 = *(const bf16x8*)(ap + 16*TD + k0);
    bf16x8 a2 = *(const bf16x8*)(ap + 32*TD + k0);
    bf16x8 a3 = *(const bf16x8*)(ap + 48*TD + k0);
    acc[0][0] = __builtin_amdgcn_mfma_f32_16x16x32_bf16(a0, b0, acc[0][0], 0,0,0);
    acc[0][1] = __builtin_amdgcn_mfma_f32_16x16x32_bf16(a0, b1, acc[0][1], 0,0,0);
    acc[1][0] = __builtin_amdgcn_mfma_f32_16x16x32_bf16(a1, b0, acc[1][0], 0,0,0);
    acc[1][1] = __builtin_amdgcn_mfma_f32_16x16x32_bf16(a1, b1, acc[1][1], 0,0,0);
    acc[2][0] = __builtin_amdgcn_mfma_f32_16x16x32_bf16(a2, b0, acc[2][0], 0,0,0);
    acc[2][1] = __builtin_amdgcn_mfma_f32_16x16x32_bf16(a2, b1, acc[2][1], 0,0,0);
    acc[3][0] = __builtin_amdgcn_mfma_f32_16x16x32_bf16(a3, b0, acc[3][0], 0,0,0);
    acc[3][1] = __builtin_amdgcn_mfma_f32_16x16x32_bf16(a3, b1, acc[3][1], 0,0,0);
  }
  #pragma unroll
  for (int mf=0; mf<4; ++mf){
    #pragma unroll
    for (int nf=0; nf<2; ++nf){
      int n = n0 + nf*16 + r15;
      #pragma unroll
      for (int qq=0; qq<4; ++qq){
        float v = acc[mf][nf][qq];
        int m = wr*64 + mf*16 + kg*4 + qq;
        if (blockIdx.z == 0){
          if (oF0) oF0[(size_t)m*TD + n] = v;
          if (oB0) oB0[(size_t)m*TD + n] = f2b(v);
        } else {
          oBT1[((size_t)(m>>5)*TD + n)*TS + (m&31)] = f2b(v);
        }
      }
    }
  }
}

// ---- qk[s,e] = scale * sum_d q[s,d] * Wk[d,e]  -- grid (32 s, 4 e-chunks), d split 4-way ----
__global__ void k_prep_qk(const float* __restrict__ q, const float* __restrict__ Wk,
                          float* __restrict__ qk){
  __shared__ float sq[TD];
  __shared__ f32x4 part[4][64];
  int s = blockIdx.x;
  int tid = threadIdx.x;
  int ds = tid >> 6, e4 = tid & 63;
  int e = blockIdx.y*256 + e4*4;
  for (int i = tid; i < TD; i += 256) sq[i] = q[s*TD + i];
  __syncthreads();
  f32x4 acc = {0,0,0,0};
  int d0 = ds*256;
  #pragma unroll 4
  for (int d = d0; d < d0+256; ++d){
    float4 w = *(const float4*)(Wk + (size_t)d*TD + e);
    float sv = sq[d];
    acc[0] += sv*w.x; acc[1] += sv*w.y; acc[2] += sv*w.z; acc[3] += sv*w.w;
  }
  part[ds][e4] = acc;
  __syncthreads();
  if (ds == 0){
    f32x4 t = part[0][e4];
    f32x4 t1 = part[1][e4], t2 = part[2][e4], t3 = part[3][e4];
    const float scale = 1.0f/32.0f;
    float4 o;
    o.x = (t[0]+t1[0]+t2[0]+t3[0])*scale;
    o.y = (t[1]+t1[1]+t2[1]+t3[1])*scale;
    o.z = (t[2]+t1[2]+t2[2]+t3[2])*scale;
    o.w = (t[3]+t1[3]+t2[3]+t3[3])*scale;
    *(float4*)(qk + (size_t)s*TD + e) = o;
  }
}

// ---- single pass over x: convert to bf16 AND compute write logits wqk[bt] ----
__global__ void k_conv_dot(const float* __restrict__ x, const float* __restrict__ qk,
                           u16* __restrict__ xb, float* __restrict__ wqk){
  int lane = threadIdx.x & 63, wv = threadIdx.x >> 6;
  long bt0 = (long)blockIdx.x * 16;
  int sseg = (int)((bt0 & (TT-1)) >> 8);   // uniform across block (16 | 256)
  float qv[16];
  #pragma unroll
  for (int i=0;i<4;i++){
    float4 t = *(const float4*)(qk + (size_t)sseg*TD + i*256 + lane*4);
    qv[i*4+0]=t.x; qv[i*4+1]=t.y; qv[i*4+2]=t.z; qv[i*4+3]=t.w;
  }
  for (int tok = wv; tok < 16; tok += 4){
    long bt = bt0 + tok;
    const float* xr = x + bt*TD;
    float dot = 0.f;
    #pragma unroll
    for (int i=0;i<4;i++){
      float4 t = *(const float4*)(xr + i*256 + lane*4);
      ushort4 u; u.x=f2b(t.x); u.y=f2b(t.y); u.z=f2b(t.z); u.w=f2b(t.w);
      *(ushort4*)(xb + bt*TD + i*256 + lane*4) = u;
      dot += t.x*qv[i*4] + t.y*qv[i*4+1] + t.z*qv[i*4+2] + t.w*qv[i*4+3];
    }
    #pragma unroll
    for (int o=32;o;o>>=1) dot += __shfl_xor(dot, o);
    if (lane == 0) wqk[bt] = dot;
  }
}

// ---- per (b,s,dchunk): softmax (recomputed per block), xbar d-slice (bf16 out) ----
__global__ void k_wattn(const float* __restrict__ wqk, const u16* __restrict__ xb,
                        u16* __restrict__ xbarb){
  __shared__ float sw[TL];
  __shared__ float red[8];
  __shared__ f32x4 part[4][64];
  int tid = threadIdx.x, lane = tid & 63, wv = tid >> 6;
  int b = blockIdx.x >> 5, s = blockIdx.x & 31;
  long base = (long)b*TT + (long)s*TL;
  float v = wqk[base + tid];
  float m = v;
  #pragma unroll
  for (int o=32;o;o>>=1) m = fmaxf(m, __shfl_xor(m, o));
  if (lane == 0) red[wv] = m;
  __syncthreads();
  m = fmaxf(fmaxf(red[0], red[1]), fmaxf(red[2], red[3]));
  float e = __expf(v - m);
  float sm = e;
  #pragma unroll
  for (int o=32;o;o>>=1) sm += __shfl_xor(sm, o);
  if (lane == 0) red[4+wv] = sm;
  __syncthreads();
  sm = red[4]+red[5]+red[6]+red[7];
  sw[tid] = e / sm;
  __syncthreads();
  int d = blockIdx.y*256 + lane*4;
  const u16* xp = xb + (base + wv*64)*TD + d;
  f32x4 acc = {0,0,0,0};
  #pragma unroll 8
  for (int i=0; i<64; ++i){
    float w = sw[wv*64 + i];
    ushort4 u = *(const ushort4*)(xp + (size_t)i*TD);
    acc[0] += w*b2f(u.x); acc[1] += w*b2f(u.y); acc[2] += w*b2f(u.z); acc[3] += w*b2f(u.w);
  }
  part[wv][lane] = acc;
  __syncthreads();
  if (wv == 0){
    f32x4 t0 = part[0][lane], t1 = part[1][lane], t2 = part[2][lane], t3 = part[3][lane];
    ushort4 o;
    o.x = f2b(t0[0]+t1[0]+t2[0]+t3[0]);
    o.y = f2b(t0[1]+t1[1]+t2[1]+t3[1]);
    o.z = f2b(t0[2]+t1[2]+t2[2]+t3[2]);
    o.w = f2b(t0[3]+t1[3]+t2[3]+t3[3]);
    *(ushort4*)(xbarb + ((size_t)b*TS + s)*TD + d) = o;
  }
}

// ---- small matmul (coalesced modeT=0 only): C = A[128,1024] @ W * scale -> bf16 ----
__global__ void k_mm(const float* __restrict__ A, const float* __restrict__ W,
                     int modeT, float scale,
                     float* __restrict__ Cf, float* __restrict__ Cf2,
                     u16* __restrict__ Cb, u16* __restrict__ CbT){
  __shared__ float sA[2][TD];
  int r0 = blockIdx.x*2;
  int n = blockIdx.y*256 + threadIdx.x;
  for (int i=threadIdx.x; i<2*TD; i+=256) sA[i>>10][i&1023] = A[(size_t)r0*TD + i];
  __syncthreads();
  float acc0=0.f, acc1=0.f;
  for (int k=0;k<TD;k+=4){
    float w0 = W[(size_t)k*TD + n],     w1 = W[(size_t)(k+1)*TD + n];
    float w2 = W[(size_t)(k+2)*TD + n], w3 = W[(size_t)(k+3)*TD + n];
    float4 a0 = *(const float4*)(&sA[0][k]);
    float4 a1 = *(const float4*)(&sA[1][k]);
    acc0 += w0*a0.x + w1*a0.y + w2*a0.z + w3*a0.w;
    acc1 += w0*a1.x + w1*a1.y + w2*a1.z + w3*a1.w;
  }
  #pragma unroll
  for (int r=0;r<2;r++){
    float v = (r==0?acc0:acc1)*scale;
    int rr = r0 + r;
    size_t idx = (size_t)rr*TD + n;
    if (Cf)  Cf[idx]  = v;
    if (Cb)  Cb[idx]  = f2b(v);
  }
}

// ---- read-attention weights: QK^T (MFMA) + masked softmax -> normalized P [BT][32] bf16 ----
__global__ __launch_bounds__(256) void k_pattn(const u16* __restrict__ xb, const u16* __restrict__ rkb,
                                               u16* __restrict__ P){
  int tid = threadIdx.x, lane = tid & 63, wv = tid >> 6;
  long bt0 = (long)blockIdx.x * 64;
  int b = (int)(bt0 >> 13);
  int smin = (int)((bt0 & (TT-1)) >> 8);
  int r15 = lane & 15, kg = lane >> 4;

  long tw = bt0 + wv*16;
  const u16* ap  = xb  + (size_t)(tw + r15)*TD + kg*8;
  const u16* bp0 = rkb + ((size_t)(b*TS + r15))*TD + kg*8;
  const u16* bp1 = rkb + ((size_t)(b*TS + 16 + r15))*TD + kg*8;
  f32x4 p0 = {0,0,0,0}, p1 = {0,0,0,0};
  #pragma unroll 4
  for (int ks=0; ks<32; ++ks){
    bf16x8 a  = *(const bf16x8*)(ap  + ks*32);
    bf16x8 b0 = *(const bf16x8*)(bp0 + ks*32);
    bf16x8 b1 = *(const bf16x8*)(bp1 + ks*32);
    p0 = __builtin_amdgcn_mfma_f32_16x16x32_bf16(a, b0, p0, 0,0,0);
    p1 = __builtin_amdgcn_mfma_f32_16x16x32_bf16(a, b1, p1, 0,0,0);
  }
  bool msk0 = (r15 < smin), msk1 = (16 + r15 < smin);
  #pragma unroll
  for (int q=0;q<4;q++){
    float l0 = msk0 ? -1e30f : p0[q];
    float l1 = msk1 ? -1e30f : p1[q];
    float mx = fmaxf(l0, l1);
    #pragma unroll
    for (int o=1;o<16;o<<=1) mx = fmaxf(mx, __shfl_xor(mx, o));
    float e0 = msk0 ? 0.f : __expf(l0 - mx);
    float e1 = msk1 ? 0.f : __expf(l1 - mx);
    float smv = e0 + e1;
    #pragma unroll
    for (int o=1;o<16;o<<=1) smv += __shfl_xor(smv, o);
    float rs = 1.f/smv;
    long trow = tw + 4*kg + q;
    P[trow*TS + r15]      = f2b(e0*rs);
    P[trow*TS + 16 + r15] = f2b(e1*rs);
  }
}

// ---- big MFMA GEMM: C[32768,1024] = A @ W^T  (R5-measured tile body + SIG fusion) ----
template<bool SIG>
__global__ __launch_bounds__(512, 2) void k_gemm(const u16* __restrict__ A, const u16* __restrict__ Bw,
                                                 const float* __restrict__ bias, void* __restrict__ Cp,
                                                 const u16* __restrict__ P, const u16* __restrict__ rvT){
  __shared__ __align__(16) char sL[131072];
  int tid = threadIdx.x, lane = tid & 63, wv = tid >> 6;
  int bid = blockIdx.x;
  int wg = ((bid & 7) << 6) | (bid >> 3);   // XCD swizzle, 512 % 8 == 0 -> bijective
  int nt = wg & 3, mt = wg >> 2;
  int m0 = mt*256, n0 = nt*256;
  int wr = wv >> 2, wc = wv & 3;
  int r15 = lane & 15, kg = lane >> 4;

  int ard[8], brd[4];
  #pragma unroll
  for (int i=0;i<8;i++){ int row = wr*128 + i*16 + r15; ard[i] = (row*64 + kg*16) ^ ((row&7)<<4); }
  #pragma unroll
  for (int j=0;j<4;j++){ int row = wc*64  + j*16 + r15; brd[j] = (row*64 + kg*16) ^ ((row&7)<<4); }

  const u16* asrc[2]; const u16* bsrc[2]; int ldst[2];
  #pragma unroll
  for (int r=0;r<2;r++){
    int S  = (r*8 + wv)*64 + lane;
    int r1 = (S>>3)&1, r2 = (S>>4)&1;
    int r0 = ((S>>2)&1) ^ r2;
    int row = ((S>>3)<<1) | r0;
    int kh  = (S&3) ^ ((r1<<1) | r0);
    asrc[r] = A  + (size_t)(m0 + row)*TD + kh*8;
    bsrc[r] = Bw + (size_t)(n0 + row)*TD + kh*8;
    ldst[r] = (r*8 + wv)*1024;
  }

  f32x4 acc[8][4];
  #pragma unroll
  for (int i=0;i<8;i++){
    #pragma unroll
    for (int j=0;j<4;j++){ f32x4 z = {0,0,0,0}; acc[i][j] = z; }
  }

  auto stageA = [&](int t){
    char* slot = sL + (size_t)(t&3)*32768;
    int k0 = t*32;
    gll16(asrc[0] + k0, slot + ldst[0]);
    gll16(asrc[1] + k0, slot + ldst[1]);
  };
  auto stageB = [&](int t){
    char* slot = sL + (size_t)(t&3)*32768;
    int k0 = t*32;
    gll16(bsrc[0] + k0, slot + 16384 + ldst[0]);
    gll16(bsrc[1] + k0, slot + 16384 + ldst[1]);
  };

  auto tile = [&](int t, bool prefetch){
    const char* sa = sL + (size_t)(t&3)*32768;
    const char* sb = sa + 16384;
    // phase 0
    bf16x8 bfg[4], af[4];
    #pragma unroll
    for (int j=0;j<4;j++) bfg[j] = *(const bf16x8*)(sb + brd[j]);
    #pragma unroll
    for (int i=0;i<4;i++) af[i] = *(const bf16x8*)(sa + ard[i]);
    if (prefetch) stageA(t+3);
    __builtin_amdgcn_s_barrier();
    LGKM0();
    __builtin_amdgcn_sched_barrier(0);
    __builtin_amdgcn_s_setprio(1);
    #pragma unroll
    for (int i=0;i<4;i++){
      #pragma unroll
      for (int j=0;j<4;j++)
        acc[i][j] = __builtin_amdgcn_mfma_f32_16x16x32_bf16(af[i], bfg[j], acc[i][j], 0,0,0);
    }
    __builtin_amdgcn_s_setprio(0);
    // phase 1
    bf16x8 af2[4];
    #pragma unroll
    for (int i=0;i<4;i++) af2[i] = *(const bf16x8*)(sa + ard[4+i]);
    if (prefetch) stageB(t+3);
    __builtin_amdgcn_s_barrier();
    LGKM0();
    __builtin_amdgcn_sched_barrier(0);
    __builtin_amdgcn_s_setprio(1);
    #pragma unroll
    for (int i=0;i<4;i++){
      #pragma unroll
      for (int j=0;j<4;j++)
        acc[4+i][j] = __builtin_amdgcn_mfma_f32_16x16x32_bf16(af2[i], bfg[j], acc[4+i][j], 0,0,0);
    }
    __builtin_amdgcn_s_setprio(0);
  };

  stageA(0); stageB(0); stageA(1); stageB(1); stageA(2); stageB(2);

  for (int t=0; t<30; ++t){
    VMWAIT(8);
    __builtin_amdgcn_s_barrier();
    tile(t, t < 29);
  }
  VMWAIT(4); __builtin_amdgcn_s_barrier(); tile(30, false);
  VMWAIT(0); __builtin_amdgcn_s_barrier(); tile(31, false);

  // epilogue: C row = kg*4+q, col = r15
  if (SIG){
    int b = m0 >> 13;
    bf16x8 vfrag[4];
    #pragma unroll
    for (int j=0;j<4;j++){
      int n = n0 + wc*64 + j*16 + r15;
      vfrag[j] = *(const bf16x8*)(rvT + ((size_t)b*TD + n)*TS + kg*8);
    }
    #pragma unroll
    for (int i=0;i<8;i++){
      int tokbase = m0 + wr*128 + i*16;
      bf16x8 pfrag = *(const bf16x8*)(P + (size_t)(tokbase + r15)*TS + kg*8);
      f32x4 rd[4];
      #pragma unroll
      for (int j=0;j<4;j++){
        f32x4 z = {0,0,0,0};
        rd[j] = __builtin_amdgcn_mfma_f32_16x16x32_bf16(pfrag, vfrag[j], z, 0,0,0);
      }
      int mrow = tokbase + kg*4;
      #pragma unroll
      for (int j=0;j<4;j++){
        int n = n0 + wc*64 + j*16 + r15;
        float bj = bias[n];
        #pragma unroll
        for (int q=0;q<4;q++){
          float g = 1.f/(1.f + __expf(-(acc[i][j][q] + bj)));
          size_t idx = (size_t)(mrow + q)*TD + n;
          float xv = b2f(A[idx]);   // A == xb
          ((u16*)Cp)[idx] = f2b(xv + g*rd[j][q]);
        }
      }
    }
  } else {
    #pragma unroll
    for (int i=0;i<8;i++){
      int mrow = m0 + wr*128 + i*16 + kg*4;
      #pragma unroll
      for (int j=0;j<4;j++){
        int n = n0 + wc*64 + j*16 + r15;
        #pragma unroll
        for (int q=0;q<4;q++){
          size_t idx = (size_t)(mrow + q)*TD + n;
          ((float*)Cp)[idx] = acc[i][j][q];
        }
      }
    }
  }
}

extern "C" void kernel_launch(void* const* d_in, const int* in_sizes, int n_in,
                              void* d_out, int out_size, void* d_ws, size_t ws_size,
                              hipStream_t stream){
  const float* x   = (const float*)d_in[0];
  const float* gw  = (const float*)d_in[1];
  const float* gb  = (const float*)d_in[2];
  const float* rqw = (const float*)d_in[3];
  const float* rkw = (const float*)d_in[4];
  const float* rvw = (const float*)d_in[5];
  const float* ow  = (const float*)d_in[6];
  const float* ms  = (const float*)d_in[7];
  const float* wqw = (const float*)d_in[8];
  const float* wkw = (const float*)d_in[9];
  const float* wvw = (const float*)d_in[10];
  float* out = (float*)d_out;
  float* mem_out = out + (size_t)BT*TD;   // byte offset 134217728

  // d_out scratch (all dead before their regions are overwritten):
  // [0,64MB)       xb   bf16 copy of x
  // [64MB,66MB)    Pb
  // [66MB,...)     bf16 weights + small bf16 tensors (consumed by dispatch #10)
  char* o = (char*)d_out;
  u16* xb    = (u16*)o;
  u16* Pb    = (u16*)(o + 67108864);
  u16* gwb   = (u16*)(o + 69206016);
  u16* wvwb  = (u16*)(o + 71303168);
  u16* rkwb  = (u16*)(o + 73400320);
  u16* rvwb  = (u16*)(o + 75497472);
  u16* wqwb  = (u16*)(o + 77594624);
  u16* msb   = (u16*)(o + 79691776);     // 64KB
  u16* xbarb = (u16*)(o + 79757312);     // 256KB
  u16* memb  = (u16*)(o + 80019456);     // 256KB
  u16* rvT   = (u16*)(o + 80281600);     // 256KB -> ends ~80.5MB < 128MB

  char* w = (char*)d_ws;
  u16*   gy    = (u16*)(w);                    // 64MB (y = x + g*read)
  float* wqkb  = (float*)(w + 67108864);       // 128KB
  float* qb    = (float*)(w + 67239936);       // 128KB
  float* qkb   = (float*)(w + 67371008);       // 128KB
  float* rkbf  = (float*)(w + 67502080);       // 512KB
  u16*   rkb   = (u16*)(w + 68026368);         // 256KB
  u16*   owb   = (u16*)(w + 68288512);         // 2MB -> ~70.4MB total ws

  k_convw<<<6176,256,0,stream>>>(gw, ow, wvw, rkw, rvw, wqw, ms,
                                 gwb, owb, wvwb, rkwb, rvwb, wqwb, msb);
  // q = ms @ Wq^T (f32)
  k_q32<<<8,512,0,stream>>>(msb, wqwb, qb);
  // qk = scale * q @ Wk
  k_prep_qk<<<dim3(32,4),256,0,stream>>>(qb, wkw, qkb);
  // xb = bf16(x); wqk = x . qk[seg]
  k_conv_dot<<<2048,256,0,stream>>>(x, qkb, xb, wqkb);
  // xbar = softmax(wqk) . x  (bf16)
  k_wattn<<<dim3(128,4),256,0,stream>>>(wqkb, xb, xbarb);
  // memory = xbar @ Wv^T  -> memb bf16 + mem_out f32
  k_smm128<<<dim3(8,1,1),512,0,stream>>>(xbarb, wvwb, wvwb, mem_out, memb, nullptr);
  // rk = memory @ Wrk^T (f32) ; rv = memory @ Wrv^T -> rvT bf16 [b][d][s]
  k_smm128<<<dim3(8,1,2),512,0,stream>>>(memb, rkwb, rvwb, rkbf, nullptr, rvT);
  // rk~ = scale * rk @ Wrq -> bf16 [b*s][d]
  k_mm<<<dim3(64,4),256,0,stream>>>(rkbf, rqw, 0, 1.f/32.f, nullptr, nullptr, rkb, nullptr);
  // P = softmax(mask(xb @ rk~^T)) normalized, bf16 [BT][32]
  k_pattn<<<512,256,0,stream>>>(xb, rkb, Pb);
  // y = x + sigmoid(x@gate_w^T + gb) * (P @ rvT)   [fused]
  k_gemm<true><<<512,512,0,stream>>>(xb, gwb, gb, gy, Pb, rvT);
  // out = y @ output_w^T
  k_gemm<false><<<512,512,0,stream>>>(gy, owb, nullptr, d_out, nullptr, nullptr);
}